// Round 1
// baseline (3138.416 us; speedup 1.0000x reference)
//
#include <hip/hip_runtime.h>
#include <hip/hip_bf16.h>
#include <math.h>

// Problem: h = z @ W + b  (z [N,256] fp32, W [256,256] fp32, b [256])
//          out[e] = sigmoid(dot(h[src[e]], h[dst[e]]))  for E edges
// N = 100000, E = 300000, D = 256.
//
// Phase 1: tiled fp32 GEMM into d_ws (102.4 MB). No fp32 MFMA on CDNA4 ->
// vector FMA, compute-bound at ~157 TF ceiling.
// Phase 2: 16 lanes per edge, float4 gathers (L3-resident h), shuffle reduce.

#define D_DIM 256
#define BM 64
#define BK 32

__global__ __launch_bounds__(256, 2) void gemm_bias_kernel(
    const float* __restrict__ z, const float* __restrict__ W,
    const float* __restrict__ b, float* __restrict__ h, int nrows) {
  __shared__ float zs[BM][BK];      // 8 KB
  __shared__ float ws[BK][D_DIM];   // 32 KB
  const int tid = threadIdx.x;
  const int tx = tid & 63;          // col group: cols 4*tx .. 4*tx+3
  const int ty = tid >> 6;          // row group: rows ty*16 .. ty*16+15
  const int row0 = blockIdx.x * BM;

  float acc[16][4];
#pragma unroll
  for (int r = 0; r < 16; r++)
#pragma unroll
    for (int c = 0; c < 4; c++) acc[r][c] = 0.f;

  for (int k0 = 0; k0 < D_DIM; k0 += BK) {
    // stage z tile: 64 rows x 32 k = 512 float4, 2 per thread
#pragma unroll
    for (int i = 0; i < 2; i++) {
      int idx4 = i * 256 + tid;       // 0..511
      int r = idx4 >> 3;              // 8 float4 per row
      int c4 = idx4 & 7;
      int gr = row0 + r;
      gr = gr < nrows ? gr : (nrows - 1);   // clamp; unused rows never stored
      float4 v = *(const float4*)(z + (size_t)gr * D_DIM + k0 + c4 * 4);
      *(float4*)(&zs[r][c4 * 4]) = v;
    }
    // stage W tile: 32 k x 256 cols = 2048 float4, 8 per thread
#pragma unroll
    for (int i = 0; i < 8; i++) {
      int idx4 = i * 256 + tid;       // 0..2047
      int r = idx4 >> 6;              // 64 float4 per row
      int c4 = idx4 & 63;
      float4 v = *(const float4*)(W + (size_t)(k0 + r) * D_DIM + c4 * 4);
      *(float4*)(&ws[r][c4 * 4]) = v;
    }
    __syncthreads();

#pragma unroll
    for (int k = 0; k < BK; k += 4) {
      float4 wv0 = *(const float4*)(&ws[k + 0][tx * 4]);
      float4 wv1 = *(const float4*)(&ws[k + 1][tx * 4]);
      float4 wv2 = *(const float4*)(&ws[k + 2][tx * 4]);
      float4 wv3 = *(const float4*)(&ws[k + 3][tx * 4]);
#pragma unroll
      for (int r = 0; r < 16; r++) {
        float4 zv = *(const float4*)(&zs[ty * 16 + r][k]);  // broadcast in wave
        acc[r][0] += zv.x * wv0.x + zv.y * wv1.x + zv.z * wv2.x + zv.w * wv3.x;
        acc[r][1] += zv.x * wv0.y + zv.y * wv1.y + zv.z * wv2.y + zv.w * wv3.y;
        acc[r][2] += zv.x * wv0.z + zv.y * wv1.z + zv.z * wv2.z + zv.w * wv3.z;
        acc[r][3] += zv.x * wv0.w + zv.y * wv1.w + zv.z * wv2.w + zv.w * wv3.w;
      }
    }
    __syncthreads();
  }

  float4 bv = *(const float4*)(b + tx * 4);
#pragma unroll
  for (int r = 0; r < 16; r++) {
    int row = row0 + ty * 16 + r;
    if (row < nrows) {
      float4 o;
      o.x = acc[r][0] + bv.x;
      o.y = acc[r][1] + bv.y;
      o.z = acc[r][2] + bv.z;
      o.w = acc[r][3] + bv.w;
      *(float4*)(h + (size_t)row * D_DIM + tx * 4) = o;
    }
  }
}

// 16 lanes per edge; each lane covers 16 floats (4x float4) of the 256-dim row.
__global__ __launch_bounds__(256) void edge_dot_kernel(
    const int* __restrict__ ei, const float* __restrict__ h,
    float* __restrict__ out, int E) {
  int gid = blockIdx.x * blockDim.x + threadIdx.x;
  int e = gid >> 4;
  int lane = gid & 15;
  if (e >= E) return;
  int s = ei[e];
  int d = ei[E + e];
  const float4* sp = (const float4*)(h + (size_t)s * D_DIM);
  const float4* dp = (const float4*)(h + (size_t)d * D_DIM);
  float acc = 0.f;
#pragma unroll
  for (int j = 0; j < 4; j++) {
    float4 a = sp[j * 16 + lane];
    float4 c = dp[j * 16 + lane];
    acc += a.x * c.x + a.y * c.y + a.z * c.z + a.w * c.w;
  }
  acc += __shfl_xor(acc, 1);
  acc += __shfl_xor(acc, 2);
  acc += __shfl_xor(acc, 4);
  acc += __shfl_xor(acc, 8);
  if (lane == 0) {
    out[e] = 1.0f / (1.0f + expf(-acc));
  }
}

extern "C" void kernel_launch(void* const* d_in, const int* in_sizes, int n_in,
                              void* d_out, int out_size, void* d_ws, size_t ws_size,
                              hipStream_t stream) {
  const float* z  = (const float*)d_in[0];
  const int*   ei = (const int*)d_in[1];
  const float* W  = (const float*)d_in[2];
  const float* b  = (const float*)d_in[3];
  float* out = (float*)d_out;
  float* h   = (float*)d_ws;   // 100000*256*4 = 102.4 MB scratch

  const int nnodes = in_sizes[0] / D_DIM;
  const int E = in_sizes[1] / 2;

  dim3 blk(256);
  dim3 grid_gemm((nnodes + BM - 1) / BM);
  gemm_bias_kernel<<<grid_gemm, blk, 0, stream>>>(z, W, b, h, nnodes);

  dim3 grid_edge(((size_t)E * 16 + 255) / 256);
  edge_dot_kernel<<<grid_edge, blk, 0, stream>>>(ei, h, out, E);
}

// Round 2
// 533.831 us; speedup vs baseline: 5.8790x; 5.8790x over previous
//
#include <hip/hip_runtime.h>
#include <hip/hip_bf16.h>
#include <math.h>

// Problem: h = z @ W + b  (z [N,256] fp32, W [256,256] fp32, b [256])
//          out[e] = sigmoid(dot(h[src[e]], h[dst[e]]))  for E edges
// N = 100000, E = 300000, D = 256.
//
// R2: fp32 GEMM restructured to kill scratch spill seen in R1
// (WRITE_SIZE 6.3 GB vs 0.1 GB ideal): acc tile 8x4 = 32 VGPRs,
// BM=64 x BN=128, LDS 24 KB, no min-waves launch_bounds hint.

#define D_DIM 256
#define BM 64
#define BN 128
#define BK 32

__global__ __launch_bounds__(256) void gemm_bias_kernel(
    const float* __restrict__ z, const float* __restrict__ W,
    const float* __restrict__ b, float* __restrict__ h, int nrows) {
  __shared__ float zs[BM][BK];      // 8 KB
  __shared__ float ws[BK][BN];      // 16 KB
  const int tid = threadIdx.x;
  const int tx = tid & 31;          // col group: cols col0 + 4*tx .. +3
  const int ty = tid >> 5;          // 0..7 -> rows ty*8 .. ty*8+7
  const int row0 = blockIdx.y * BM;
  const int col0 = blockIdx.x * BN;

  float acc[8][4];
#pragma unroll
  for (int r = 0; r < 8; r++)
#pragma unroll
    for (int c = 0; c < 4; c++) acc[r][c] = 0.f;

  for (int k0 = 0; k0 < D_DIM; k0 += BK) {
    // stage z tile: 64 rows x 32 k = 512 float4, 2 per thread
#pragma unroll
    for (int i = 0; i < 2; i++) {
      int idx4 = i * 256 + tid;       // 0..511
      int r = idx4 >> 3;              // 8 float4 per row
      int c4 = idx4 & 7;
      int gr = row0 + r;
      gr = gr < nrows ? gr : (nrows - 1);   // clamp; padded rows never stored
      float4 v = *(const float4*)(z + (size_t)gr * D_DIM + k0 + c4 * 4);
      *(float4*)(&zs[r][c4 * 4]) = v;
    }
    // stage W tile: 32 k x 128 cols = 1024 float4, 4 per thread
#pragma unroll
    for (int i = 0; i < 4; i++) {
      int idx4 = i * 256 + tid;       // 0..1023
      int r = idx4 >> 5;              // 32 float4 per row-strip
      int c4 = idx4 & 31;
      float4 v = *(const float4*)(W + (size_t)(k0 + r) * D_DIM + col0 + c4 * 4);
      *(float4*)(&ws[r][c4 * 4]) = v;
    }
    __syncthreads();

#pragma unroll
    for (int k = 0; k < BK; k += 4) {
      float4 wv0 = *(const float4*)(&ws[k + 0][tx * 4]);
      float4 wv1 = *(const float4*)(&ws[k + 1][tx * 4]);
      float4 wv2 = *(const float4*)(&ws[k + 2][tx * 4]);
      float4 wv3 = *(const float4*)(&ws[k + 3][tx * 4]);
#pragma unroll
      for (int r = 0; r < 8; r++) {
        float4 zv = *(const float4*)(&zs[ty * 8 + r][k]);  // 32-lane broadcast
        acc[r][0] += zv.x * wv0.x + zv.y * wv1.x + zv.z * wv2.x + zv.w * wv3.x;
        acc[r][1] += zv.x * wv0.y + zv.y * wv1.y + zv.z * wv2.y + zv.w * wv3.y;
        acc[r][2] += zv.x * wv0.z + zv.y * wv1.z + zv.z * wv2.z + zv.w * wv3.z;
        acc[r][3] += zv.x * wv0.w + zv.y * wv1.w + zv.z * wv2.w + zv.w * wv3.w;
      }
    }
    __syncthreads();
  }

  float4 bv = *(const float4*)(b + col0 + tx * 4);
#pragma unroll
  for (int r = 0; r < 8; r++) {
    int row = row0 + ty * 8 + r;
    if (row < nrows) {
      float4 o;
      o.x = acc[r][0] + bv.x;
      o.y = acc[r][1] + bv.y;
      o.z = acc[r][2] + bv.z;
      o.w = acc[r][3] + bv.w;
      *(float4*)(h + (size_t)row * D_DIM + col0 + tx * 4) = o;
    }
  }
}

// 16 lanes per edge; each lane covers 16 floats (4x float4) of the 256-dim row.
__global__ __launch_bounds__(256) void edge_dot_kernel(
    const int* __restrict__ ei, const float* __restrict__ h,
    float* __restrict__ out, int E) {
  int gid = blockIdx.x * blockDim.x + threadIdx.x;
  int e = gid >> 4;
  int lane = gid & 15;
  if (e >= E) return;
  int s = ei[e];
  int d = ei[E + e];
  const float4* sp = (const float4*)(h + (size_t)s * D_DIM);
  const float4* dp = (const float4*)(h + (size_t)d * D_DIM);
  float acc = 0.f;
#pragma unroll
  for (int j = 0; j < 4; j++) {
    float4 a = sp[j * 16 + lane];
    float4 c = dp[j * 16 + lane];
    acc += a.x * c.x + a.y * c.y + a.z * c.z + a.w * c.w;
  }
  acc += __shfl_xor(acc, 1);
  acc += __shfl_xor(acc, 2);
  acc += __shfl_xor(acc, 4);
  acc += __shfl_xor(acc, 8);
  if (lane == 0) {
    out[e] = 1.0f / (1.0f + expf(-acc));
  }
}

extern "C" void kernel_launch(void* const* d_in, const int* in_sizes, int n_in,
                              void* d_out, int out_size, void* d_ws, size_t ws_size,
                              hipStream_t stream) {
  const float* z  = (const float*)d_in[0];
  const int*   ei = (const int*)d_in[1];
  const float* W  = (const float*)d_in[2];
  const float* b  = (const float*)d_in[3];
  float* out = (float*)d_out;
  float* h   = (float*)d_ws;   // 100000*256*4 = 102.4 MB scratch

  const int nnodes = in_sizes[0] / D_DIM;
  const int E = in_sizes[1] / 2;

  dim3 blk(256);
  dim3 grid_gemm(D_DIM / BN, (nnodes + BM - 1) / BM);
  gemm_bias_kernel<<<grid_gemm, blk, 0, stream>>>(z, W, b, h, nnodes);

  dim3 grid_edge(((size_t)E * 16 + 255) / 256);
  edge_dot_kernel<<<grid_edge, blk, 0, stream>>>(ei, h, out, E);
}

// Round 3
// 314.583 us; speedup vs baseline: 9.9764x; 1.6969x over previous
//
#include <hip/hip_runtime.h>
#include <hip/hip_bf16.h>
#include <math.h>

// Problem: h = z @ W + b  (z [N,256] fp32, W [256,256] fp32, b [256])
//          out[e] = sigmoid(dot(h[src[e]], h[dst[e]]))  for E edges
// N = 100000, E = 300000, D = 256.
//
// R3: GEMM via split-bf16 MFMA (3-term: zh*Wh + zh*Wl + zl*Wh), which gives
// ~fp32 accuracy at bf16 MFMA rate. Memory-bound: 205 MB HBM -> ~33 us floor.
// BM=64 x BN=256 (z read exactly once), BK=32, 4 waves x 64x64 strips,
// mfma_f32_16x16x32_bf16. W split/transposed in-kernel per stage (L2-hot).

#define D_DIM 256
#define BM 64
#define BK 32

typedef __attribute__((ext_vector_type(8))) short bf16x8;
typedef __attribute__((ext_vector_type(4))) short short4v;
typedef __attribute__((ext_vector_type(4))) float f32x4;

__device__ inline unsigned short bf16_rn(float x) {
  unsigned u = __builtin_bit_cast(unsigned, x);
  unsigned r = u + 0x7FFFu + ((u >> 16) & 1u);
  return (unsigned short)(r >> 16);
}
__device__ inline float bf16_f(unsigned short s) {
  return __builtin_bit_cast(float, (unsigned)s << 16);
}

__global__ __launch_bounds__(256) void gemm_mfma_kernel(
    const float* __restrict__ z, const float* __restrict__ W,
    const float* __restrict__ b, float* __restrict__ h, int nrows) {
  // LDS: padded row stride 40 shorts (80 B) -> 16B-aligned b128 frags,
  // 2-way bank aliasing only (free per m136).
  __shared__ short zs_h[BM][40], zs_l[BM][40];     // 5 KB each
  __shared__ short ws_h[256][40], ws_l[256][40];   // 20 KB each
  const int tid = threadIdx.x;
  const int lane = tid & 63;
  const int wv = tid >> 6;        // wave 0..3 -> cols wv*64 .. +63
  const int fr = lane & 15;
  const int qd = lane >> 4;
  const int row0 = blockIdx.x * BM;

  f32x4 acc[4][4];
#pragma unroll
  for (int i = 0; i < 4; i++)
#pragma unroll
    for (int j = 0; j < 4; j++) acc[i][j] = (f32x4)0.f;

  for (int k0 = 0; k0 < D_DIM; k0 += BK) {
    // ---- stage z tile: 64 rows x 32 k fp32, convert to hi/lo bf16 ----
#pragma unroll
    for (int i = 0; i < 2; i++) {
      int idx = i * 256 + tid;          // 0..511
      int r = idx >> 3;                 // row in tile
      int c = idx & 7;                  // float4 chunk (4 fp32)
      int gr = row0 + r;
      gr = gr < nrows ? gr : (nrows - 1);
      float4 v = *(const float4*)(z + (size_t)gr * D_DIM + k0 + c * 4);
      float vv[4] = {v.x, v.y, v.z, v.w};
      short4v hi, lo;
#pragma unroll
      for (int j = 0; j < 4; j++) {
        unsigned short hb = bf16_rn(vv[j]);
        hi[j] = (short)hb;
        lo[j] = (short)bf16_rn(vv[j] - bf16_f(hb));
      }
      *(short4v*)(&zs_h[r][c * 4]) = hi;   // byte addr r*80 + c*8, 8B aligned
      *(short4v*)(&zs_l[r][c * 4]) = lo;
    }
    // ---- stage W tile transposed: ws[n][k], n=tid, 4 chunks of 8 k ----
#pragma unroll
    for (int c = 0; c < 4; c++) {
      float v[8];
#pragma unroll
      for (int j = 0; j < 8; j++)
        v[j] = W[(size_t)(k0 + c * 8 + j) * D_DIM + tid];  // lanes: consec n
      bf16x8 hi, lo;
#pragma unroll
      for (int j = 0; j < 8; j++) {
        unsigned short hb = bf16_rn(v[j]);
        hi[j] = (short)hb;
        lo[j] = (short)bf16_rn(v[j] - bf16_f(hb));
      }
      *(bf16x8*)(&ws_h[tid][c * 8]) = hi;  // byte addr tid*80 + c*16, 16B ok
      *(bf16x8*)(&ws_l[tid][c * 8]) = lo;
    }
    __syncthreads();

    // ---- fragments + MFMA triple ----
    bf16x8 ah[4], al[4];
#pragma unroll
    for (int fm = 0; fm < 4; fm++) {
      ah[fm] = *(const bf16x8*)(&zs_h[fm * 16 + fr][qd * 8]);
      al[fm] = *(const bf16x8*)(&zs_l[fm * 16 + fr][qd * 8]);
    }
#pragma unroll
    for (int fn = 0; fn < 4; fn++) {
      int n = wv * 64 + fn * 16 + fr;
      bf16x8 bh = *(const bf16x8*)(&ws_h[n][qd * 8]);
      bf16x8 bl = *(const bf16x8*)(&ws_l[n][qd * 8]);
#pragma unroll
      for (int fm = 0; fm < 4; fm++) {
        acc[fm][fn] = __builtin_amdgcn_mfma_f32_16x16x32_bf16(ah[fm], bh, acc[fm][fn], 0, 0, 0);
        acc[fm][fn] = __builtin_amdgcn_mfma_f32_16x16x32_bf16(ah[fm], bl, acc[fm][fn], 0, 0, 0);
        acc[fm][fn] = __builtin_amdgcn_mfma_f32_16x16x32_bf16(al[fm], bh, acc[fm][fn], 0, 0, 0);
      }
    }
    __syncthreads();
  }

  // ---- epilogue: C[row = qd*4+r (+fm*16), col = fr (+wv*64+fn*16)] ----
#pragma unroll
  for (int fn = 0; fn < 4; fn++) {
    int col = wv * 64 + fn * 16 + fr;
    float bias = b[col];
#pragma unroll
    for (int fm = 0; fm < 4; fm++) {
#pragma unroll
      for (int r = 0; r < 4; r++) {
        int row = row0 + fm * 16 + qd * 4 + r;
        if (row < nrows)
          h[(size_t)row * D_DIM + col] = acc[fm][fn][r] + bias;
      }
    }
  }
}

// 16 lanes per edge; each lane covers 16 floats (4x float4) of the 256-dim row.
__global__ __launch_bounds__(256) void edge_dot_kernel(
    const int* __restrict__ ei, const float* __restrict__ h,
    float* __restrict__ out, int E) {
  int gid = blockIdx.x * blockDim.x + threadIdx.x;
  int e = gid >> 4;
  int lane = gid & 15;
  if (e >= E) return;
  int s = ei[e];
  int d = ei[E + e];
  const float4* sp = (const float4*)(h + (size_t)s * D_DIM);
  const float4* dp = (const float4*)(h + (size_t)d * D_DIM);
  float acc = 0.f;
#pragma unroll
  for (int j = 0; j < 4; j++) {
    float4 a = sp[j * 16 + lane];
    float4 c = dp[j * 16 + lane];
    acc += a.x * c.x + a.y * c.y + a.z * c.z + a.w * c.w;
  }
  acc += __shfl_xor(acc, 1);
  acc += __shfl_xor(acc, 2);
  acc += __shfl_xor(acc, 4);
  acc += __shfl_xor(acc, 8);
  if (lane == 0) {
    out[e] = 1.0f / (1.0f + expf(-acc));
  }
}

extern "C" void kernel_launch(void* const* d_in, const int* in_sizes, int n_in,
                              void* d_out, int out_size, void* d_ws, size_t ws_size,
                              hipStream_t stream) {
  const float* z  = (const float*)d_in[0];
  const int*   ei = (const int*)d_in[1];
  const float* W  = (const float*)d_in[2];
  const float* b  = (const float*)d_in[3];
  float* out = (float*)d_out;
  float* h   = (float*)d_ws;   // 100000*256*4 = 102.4 MB scratch

  const int nnodes = in_sizes[0] / D_DIM;
  const int E = in_sizes[1] / 2;

  dim3 blk(256);
  dim3 grid_gemm((nnodes + BM - 1) / BM);
  gemm_mfma_kernel<<<grid_gemm, blk, 0, stream>>>(z, W, b, h, nnodes);

  dim3 grid_edge(((size_t)E * 16 + 255) / 256);
  edge_dot_kernel<<<grid_edge, blk, 0, stream>>>(ei, h, out, E);
}

// Round 4
// 302.975 us; speedup vs baseline: 10.3586x; 1.0383x over previous
//
#include <hip/hip_runtime.h>
#include <hip/hip_bf16.h>
#include <math.h>

// Problem: h = z @ W + b  (z [N,256] fp32, W [256,256] fp32, b [256])
//          out[e] = sigmoid(dot(h[src[e]], h[dst[e]]))  for E edges
// N = 100000, E = 300000, D = 256.
//
// R4: zero-barrier split-bf16 MFMA GEMM.
//  - pack_w_kernel: W -> hi/lo bf16 fragments in MFMA B-layout, packed
//    contiguous per (kb,n,qd) into static __device__ arrays (L2-resident).
//  - gemm: no LDS in K-loop, no __syncthreads. A-frags loaded straight from
//    z (lane (fr,qd) pattern = 16 full 128B lines/instr), split in-reg.
//    B-frags = contiguous 16B/lane loads from packed W. 3-term MFMA
//    (zh*Wh + zh*Wl + zl*Wh) == ~fp32 accuracy at bf16 rate.
//  - epilogue: wave-private LDS transpose -> 256B-contiguous float4 stores
//    (R3 had 1.4x write amplification from 64B scalar-store segments).
//  - edge kernel: 2 edges per 16-lane group = 16 outstanding loads/lane.

#define D_DIM 256
#define BM 64

typedef __attribute__((ext_vector_type(8))) short bf16x8;
typedef __attribute__((ext_vector_type(4))) float f32x4;

__device__ bf16x8 g_Wh[8 * 256 * 4];   // [kb][n][qd] -> 16B frag, 128 KB
__device__ bf16x8 g_Wl[8 * 256 * 4];

__device__ inline unsigned short bf16_rn(float x) {
  unsigned u = __builtin_bit_cast(unsigned, x);
  unsigned r = u + 0x7FFFu + ((u >> 16) & 1u);
  return (unsigned short)(r >> 16);
}
__device__ inline float bf16_f(unsigned short s) {
  return __builtin_bit_cast(float, (unsigned)s << 16);
}

__device__ inline void split8(float4 f0, float4 f1, bf16x8& hi, bf16x8& lo) {
  float v[8] = {f0.x, f0.y, f0.z, f0.w, f1.x, f1.y, f1.z, f1.w};
#pragma unroll
  for (int j = 0; j < 8; j++) {
    unsigned short hb = bf16_rn(v[j]);
    hi[j] = (short)hb;
    lo[j] = (short)bf16_rn(v[j] - bf16_f(hb));
  }
}

// 8192 threads: t -> (kb, qd, n), n fastest => coalesced row reads of W.
__global__ __launch_bounds__(256) void pack_w_kernel(const float* __restrict__ W) {
  int t = blockIdx.x * 256 + threadIdx.x;   // 0..8191
  int kb = t >> 10;
  int qd = (t >> 8) & 3;
  int n  = t & 255;
  float4 f0, f1;
  float v[8];
#pragma unroll
  for (int j = 0; j < 8; j++)
    v[j] = W[(size_t)(kb * 32 + qd * 8 + j) * D_DIM + n];
  f0 = make_float4(v[0], v[1], v[2], v[3]);
  f1 = make_float4(v[4], v[5], v[6], v[7]);
  bf16x8 hi, lo;
  split8(f0, f1, hi, lo);
  int fi = (kb * 256 + n) * 4 + qd;
  g_Wh[fi] = hi;
  g_Wl[fi] = lo;
}

__global__ __launch_bounds__(256) void gemm_mfma_kernel(
    const float* __restrict__ z, const float* __restrict__ b,
    float* __restrict__ h, int nrows) {
  __shared__ float et[4][16][68];   // wave-private epilogue tiles, 17.4 KB
  const int tid = threadIdx.x;
  const int lane = tid & 63;
  const int wv = tid >> 6;          // wave 0..3 -> cols wv*64 .. +63
  const int fr = lane & 15;
  const int qd = lane >> 4;
  const int row0 = blockIdx.x * BM;

  f32x4 acc[4][4];
#pragma unroll
  for (int i = 0; i < 4; i++)
#pragma unroll
    for (int j = 0; j < 4; j++) acc[i][j] = (f32x4)0.f;

  int ar[4];
#pragma unroll
  for (int fm = 0; fm < 4; fm++) {
    int r = row0 + fm * 16 + fr;
    ar[fm] = r < nrows ? r : (nrows - 1);
  }

#pragma unroll 1
  for (int kb = 0; kb < 8; kb++) {
    const int k0 = kb * 32;
    // A-frags: lane (fr,qd) reads z[row][k0+qd*8 .. +7]; per instr the wave
    // covers 16 rows x 128B contiguous = 16 full lines.
    bf16x8 ah[4], al[4];
#pragma unroll
    for (int fm = 0; fm < 4; fm++) {
      const float4* p = (const float4*)(z + (size_t)ar[fm] * D_DIM + k0 + qd * 8);
      split8(p[0], p[1], ah[fm], al[fm]);
    }
    // B-frags from packed W: per (fn) the wave reads a contiguous 1 KB chunk.
    const int fbase = (kb * 256 + wv * 64) * 4 + qd;
#pragma unroll
    for (int fn = 0; fn < 4; fn++) {
      int fi = fbase + (fn * 16 + fr) * 4;
      bf16x8 bh = g_Wh[fi];
      bf16x8 bl = g_Wl[fi];
#pragma unroll
      for (int fm = 0; fm < 4; fm++) {
        acc[fm][fn] = __builtin_amdgcn_mfma_f32_16x16x32_bf16(ah[fm], bh, acc[fm][fn], 0, 0, 0);
        acc[fm][fn] = __builtin_amdgcn_mfma_f32_16x16x32_bf16(ah[fm], bl, acc[fm][fn], 0, 0, 0);
        acc[fm][fn] = __builtin_amdgcn_mfma_f32_16x16x32_bf16(al[fm], bh, acc[fm][fn], 0, 0, 0);
      }
    }
  }

  // Epilogue: C[row=qd*4+r][col=fn*16+fr] -> wave-private LDS -> float4 rows.
  float bias[4];
#pragma unroll
  for (int fn = 0; fn < 4; fn++) bias[fn] = b[wv * 64 + fn * 16 + fr];

#pragma unroll
  for (int fm = 0; fm < 4; fm++) {
#pragma unroll
    for (int fn = 0; fn < 4; fn++)
#pragma unroll
      for (int r = 0; r < 4; r++)
        et[wv][qd * 4 + r][fn * 16 + fr] = acc[fm][fn][r] + bias[fn];
    // same-wave LDS ops are ordered; no __syncthreads needed (private tile)
#pragma unroll
    for (int it = 0; it < 4; it++) {
      int rr = it * 4 + qd;       // 0..15
      float4 v = *(const float4*)(&et[wv][rr][fr * 4]);
      int row = row0 + fm * 16 + rr;
      if (row < nrows)
        *(float4*)(h + (size_t)row * D_DIM + wv * 64 + fr * 4) = v;
    }
  }
}

// 2 edges per 16-lane group: 16 outstanding 16B loads per lane (MLP x2).
__global__ __launch_bounds__(256) void edge_dot_kernel(
    const int* __restrict__ ei, const float* __restrict__ h,
    float* __restrict__ out, int E) {
  int gid = blockIdx.x * blockDim.x + threadIdx.x;
  int p = gid >> 4;
  int lane = gid & 15;
  int e0 = p * 2, e1 = p * 2 + 1;
  if (e0 >= E) return;
  bool has1 = e1 < E;
  int s0 = ei[e0],              d0 = ei[E + e0];
  int s1 = has1 ? ei[e1] : s0,  d1 = has1 ? ei[E + e1] : d0;
  const float4* sp0 = (const float4*)(h + (size_t)s0 * D_DIM);
  const float4* dp0 = (const float4*)(h + (size_t)d0 * D_DIM);
  const float4* sp1 = (const float4*)(h + (size_t)s1 * D_DIM);
  const float4* dp1 = (const float4*)(h + (size_t)d1 * D_DIM);
  float acc0 = 0.f, acc1 = 0.f;
#pragma unroll
  for (int j = 0; j < 4; j++) {
    float4 a0 = sp0[j * 16 + lane];
    float4 c0 = dp0[j * 16 + lane];
    float4 a1 = sp1[j * 16 + lane];
    float4 c1 = dp1[j * 16 + lane];
    acc0 += a0.x * c0.x + a0.y * c0.y + a0.z * c0.z + a0.w * c0.w;
    acc1 += a1.x * c1.x + a1.y * c1.y + a1.z * c1.z + a1.w * c1.w;
  }
#pragma unroll
  for (int m = 1; m <= 8; m <<= 1) {
    acc0 += __shfl_xor(acc0, m);
    acc1 += __shfl_xor(acc1, m);
  }
  if (lane == 0) {
    out[e0] = 1.0f / (1.0f + expf(-acc0));
    if (has1) out[e1] = 1.0f / (1.0f + expf(-acc1));
  }
}

extern "C" void kernel_launch(void* const* d_in, const int* in_sizes, int n_in,
                              void* d_out, int out_size, void* d_ws, size_t ws_size,
                              hipStream_t stream) {
  const float* z  = (const float*)d_in[0];
  const int*   ei = (const int*)d_in[1];
  const float* W  = (const float*)d_in[2];
  const float* b  = (const float*)d_in[3];
  float* out = (float*)d_out;
  float* h   = (float*)d_ws;   // 100000*256*4 = 102.4 MB scratch

  const int nnodes = in_sizes[0] / D_DIM;
  const int E = in_sizes[1] / 2;

  pack_w_kernel<<<32, 256, 0, stream>>>(W);

  dim3 grid_gemm((nnodes + BM - 1) / BM);
  gemm_mfma_kernel<<<grid_gemm, 256, 0, stream>>>(z, b, h, nnodes);

  int pairs = (E + 1) / 2;
  dim3 grid_edge(((size_t)pairs * 16 + 255) / 256);
  edge_dot_kernel<<<grid_edge, 256, 0, stream>>>(ei, h, out, E);
}

// Round 5
// 249.873 us; speedup vs baseline: 12.5600x; 1.2125x over previous
//
#include <hip/hip_runtime.h>
#include <hip/hip_bf16.h>
#include <hip/hip_fp16.h>
#include <math.h>

// Problem: h = z @ W + b  (z [N,256] fp32, W [256,256] fp32, b [256])
//          out[e] = sigmoid(dot(h[src[e]], h[dst[e]]))  for E edges
// N = 100000, E = 300000, D = 256.
//
// R5: (a) GEMM software pipeline: next-kb raw z prefetched into registers
//     before the MFMA block; all 8 B-frag loads (L2-hot packed W) hoisted
//     ahead of the split-bf16 convert. Zero barriers in K-loop.
//     (b) h stored as fp16 (h~N(0,1): quant noise adds ~0.008 output error,
//     under the 0.02 threshold) -> GEMM write 100->50 MB, edge gather
//     614->307 MB. 3-term split-bf16 MFMA retained for GEMM accuracy.
//     (c) edge kernel: 4 edges per 16-lane group, all 16 loads hoisted.

#define D_DIM 256
#define BM 64

typedef __attribute__((ext_vector_type(8))) short bf16x8;
typedef __attribute__((ext_vector_type(4))) float f32x4;

__device__ bf16x8 g_Wh[8 * 256 * 4];   // [kb][n][qd] -> 16B frag, 128 KB
__device__ bf16x8 g_Wl[8 * 256 * 4];

__device__ inline unsigned short bf16_rn(float x) {
  unsigned u = __builtin_bit_cast(unsigned, x);
  unsigned r = u + 0x7FFFu + ((u >> 16) & 1u);
  return (unsigned short)(r >> 16);
}
__device__ inline float bf16_f(unsigned short s) {
  return __builtin_bit_cast(float, (unsigned)s << 16);
}

__device__ inline void split8(float4 f0, float4 f1, bf16x8& hi, bf16x8& lo) {
  float v[8] = {f0.x, f0.y, f0.z, f0.w, f1.x, f1.y, f1.z, f1.w};
#pragma unroll
  for (int j = 0; j < 8; j++) {
    unsigned short hb = bf16_rn(v[j]);
    hi[j] = (short)hb;
    lo[j] = (short)bf16_rn(v[j] - bf16_f(hb));
  }
}

// 8192 threads: t -> (kb, qd, n), n fastest => coalesced row reads of W.
__global__ __launch_bounds__(256) void pack_w_kernel(const float* __restrict__ W) {
  int t = blockIdx.x * 256 + threadIdx.x;   // 0..8191
  int kb = t >> 10;
  int qd = (t >> 8) & 3;
  int n  = t & 255;
  float v[8];
#pragma unroll
  for (int j = 0; j < 8; j++)
    v[j] = W[(size_t)(kb * 32 + qd * 8 + j) * D_DIM + n];
  bf16x8 hi, lo;
  split8(make_float4(v[0], v[1], v[2], v[3]),
         make_float4(v[4], v[5], v[6], v[7]), hi, lo);
  int fi = (kb * 256 + n) * 4 + qd;
  g_Wh[fi] = hi;
  g_Wl[fi] = lo;
}

__global__ __launch_bounds__(256) void gemm_mfma_kernel(
    const float* __restrict__ z, const float* __restrict__ b,
    __half* __restrict__ h, int nrows) {
  __shared__ __half et[4][16][72];   // wave-private epilogue tiles (9.2 KB)
  const int tid = threadIdx.x;
  const int lane = tid & 63;
  const int wv = tid >> 6;          // wave 0..3 -> cols wv*64 .. +63
  const int fr = lane & 15;
  const int qd = lane >> 4;
  const int row0 = blockIdx.x * BM;

  f32x4 acc[4][4];
#pragma unroll
  for (int i = 0; i < 4; i++)
#pragma unroll
    for (int j = 0; j < 4; j++) acc[i][j] = (f32x4)0.f;

  const float* zp[4];
#pragma unroll
  for (int fm = 0; fm < 4; fm++) {
    int r = row0 + fm * 16 + fr;
    r = r < nrows ? r : (nrows - 1);
    zp[fm] = z + (size_t)r * D_DIM + qd * 8;
  }

  // preload kb=0 raw A
  float4 a0[4], a1[4];
#pragma unroll
  for (int fm = 0; fm < 4; fm++) {
    a0[fm] = *(const float4*)(zp[fm]);
    a1[fm] = *(const float4*)(zp[fm] + 4);
  }

#pragma unroll 1
  for (int kb = 0; kb < 8; kb++) {
    // B-frags for this kb: 8 x b128 from L2-hot packed W, issued first.
    bf16x8 bh[4], bl[4];
    const int fbase = (kb * 256 + wv * 64) * 4 + qd;
#pragma unroll
    for (int fn = 0; fn < 4; fn++) {
      int fi = fbase + (fn * 16 + fr) * 4;
      bh[fn] = g_Wh[fi];
      bl[fn] = g_Wl[fi];
    }
    // convert current A (overlaps B latency)
    bf16x8 ah[4], al[4];
#pragma unroll
    for (int fm = 0; fm < 4; fm++) split8(a0[fm], a1[fm], ah[fm], al[fm]);
    // prefetch next kb's raw A (HBM) -- in flight across the MFMA block
    if (kb < 7) {
#pragma unroll
      for (int fm = 0; fm < 4; fm++) {
        const float* p = zp[fm] + (kb + 1) * 32;
        a0[fm] = *(const float4*)(p);
        a1[fm] = *(const float4*)(p + 4);
      }
    }
#pragma unroll
    for (int fn = 0; fn < 4; fn++) {
#pragma unroll
      for (int fm = 0; fm < 4; fm++) {
        acc[fm][fn] = __builtin_amdgcn_mfma_f32_16x16x32_bf16(ah[fm], bh[fn], acc[fm][fn], 0, 0, 0);
        acc[fm][fn] = __builtin_amdgcn_mfma_f32_16x16x32_bf16(ah[fm], bl[fn], acc[fm][fn], 0, 0, 0);
        acc[fm][fn] = __builtin_amdgcn_mfma_f32_16x16x32_bf16(al[fm], bh[fn], acc[fm][fn], 0, 0, 0);
      }
    }
  }

  // Epilogue: C[row=qd*4+r][col=fn*16+fr] -> wave-private LDS -> 16B stores.
  float bias[4];
#pragma unroll
  for (int fn = 0; fn < 4; fn++) bias[fn] = b[wv * 64 + fn * 16 + fr];

#pragma unroll
  for (int fm = 0; fm < 4; fm++) {
#pragma unroll
    for (int fn = 0; fn < 4; fn++)
#pragma unroll
      for (int r = 0; r < 4; r++)
        et[wv][qd * 4 + r][fn * 16 + fr] = __float2half(acc[fm][fn][r] + bias[fn]);
    // same-wave LDS write->read (in-order LDS pipe per wave; verified R4)
#pragma unroll
    for (int it = 0; it < 2; it++) {
      int chunk = it * 64 + lane;     // 0..127
      int rr = chunk >> 3;            // 0..15
      int cc = chunk & 7;             // 16B chunk within 128B wave strip
      float4 v = *(const float4*)(&et[wv][rr][cc * 8]);
      int row = row0 + fm * 16 + rr;
      if (row < nrows)
        *(float4*)(h + (size_t)row * D_DIM + wv * 64 + cc * 8) = v;
    }
  }
}

// 4 edges per 16-lane group; all 16 x 16B loads hoisted (deep MLP).
__global__ __launch_bounds__(256) void edge_dot_kernel(
    const int* __restrict__ ei, const __half* __restrict__ h,
    float* __restrict__ out, int E) {
  int gid = blockIdx.x * blockDim.x + threadIdx.x;
  int g = gid >> 4;
  int lane = gid & 15;
  int ebase = g * 4;
  if (ebase >= E) return;

  float4 sv[4][2], dv[4][2];
  int ec[4];
#pragma unroll
  for (int q = 0; q < 4; q++) {
    int e = ebase + q;
    ec[q] = e < E ? e : (E - 1);
  }
#pragma unroll
  for (int q = 0; q < 4; q++) {
    int s = ei[ec[q]];
    int d = ei[E + ec[q]];
    const float4* sp = (const float4*)(h + (size_t)s * D_DIM);
    const float4* dp = (const float4*)(h + (size_t)d * D_DIM);
#pragma unroll
    for (int c = 0; c < 2; c++) {
      sv[q][c] = sp[c * 16 + lane];
      dv[q][c] = dp[c * 16 + lane];
    }
  }
  float acc[4] = {0.f, 0.f, 0.f, 0.f};
#pragma unroll
  for (int q = 0; q < 4; q++) {
#pragma unroll
    for (int c = 0; c < 2; c++) {
      const __half2* s2 = (const __half2*)&sv[q][c];
      const __half2* d2 = (const __half2*)&dv[q][c];
#pragma unroll
      for (int j = 0; j < 4; j++) {
        float2 a = __half22float2(s2[j]);
        float2 b2 = __half22float2(d2[j]);
        acc[q] += a.x * b2.x + a.y * b2.y;
      }
    }
  }
#pragma unroll
  for (int m = 1; m <= 8; m <<= 1) {
#pragma unroll
    for (int q = 0; q < 4; q++) acc[q] += __shfl_xor(acc[q], m);
  }
  if (lane == 0) {
    if (ebase + 3 < E) {
      float4 o;
      o.x = 1.0f / (1.0f + expf(-acc[0]));
      o.y = 1.0f / (1.0f + expf(-acc[1]));
      o.z = 1.0f / (1.0f + expf(-acc[2]));
      o.w = 1.0f / (1.0f + expf(-acc[3]));
      *(float4*)(out + ebase) = o;
    } else {
#pragma unroll
      for (int q = 0; q < 4; q++)
        if (ebase + q < E) out[ebase + q] = 1.0f / (1.0f + expf(-acc[q]));
    }
  }
}

extern "C" void kernel_launch(void* const* d_in, const int* in_sizes, int n_in,
                              void* d_out, int out_size, void* d_ws, size_t ws_size,
                              hipStream_t stream) {
  const float* z  = (const float*)d_in[0];
  const int*   ei = (const int*)d_in[1];
  const float* W  = (const float*)d_in[2];
  const float* b  = (const float*)d_in[3];
  float* out = (float*)d_out;
  __half* h  = (__half*)d_ws;   // 100000*256*2 = 51.2 MB scratch

  const int nnodes = in_sizes[0] / D_DIM;
  const int E = in_sizes[1] / 2;

  pack_w_kernel<<<32, 256, 0, stream>>>(W);

  dim3 grid_gemm((nnodes + BM - 1) / BM);
  gemm_mfma_kernel<<<grid_gemm, 256, 0, stream>>>(z, b, h, nnodes);

  int groups = (E + 3) / 4;
  dim3 grid_edge(((size_t)groups * 16 + 255) / 256);
  edge_dot_kernel<<<grid_edge, 256, 0, stream>>>(ei, h, out, E);
}